// Round 9
// baseline (23.641 us; speedup 1.0000x reference)
//
#include <hip/hip_runtime.h>
#include <math.h>

#define Bc 4
#define Cc 128
#define Pc 64
#define PLANE 576      // 24*24
#define VOL   13824    // 24^3
#define NI    (-INFINITY)

// One wave per (proposal, channel-pair {c, c+64}) — the R7 sweet spot.
// w-biases shared across row-chunks (validity folded into per-chunk h-masks;
// invalid rows accumulate clamped data that the merge discards). d-region
// split = 3 uniform scalar segments, each a compact templated loop with
// #pragma unroll 4 (8-10 independent loads in flight, VGPR < 128).
// Epilogue: fold channel B into lanes>=32 (one xor-32 exchange), then one
// select-exchange octant reduce over 32-lane halves; 16 lanes store.

struct Acc { float v00, v01, v10, v11; };   // [d-region][w-region]

template<int RMODE>   // 0: d-region0, 1: d-region1, 2: both (overlap plane)
__device__ __forceinline__ void upd(Acc& a, float t0, float t1) {
    if (RMODE != 1) { a.v00 = fmaxf(a.v00, t0); a.v01 = fmaxf(a.v01, t1); }
    if (RMODE != 0) { a.v10 = fmaxf(a.v10, t0); a.v11 = fmaxf(a.v11, t1); }
}

#define TREE(v, B) fmaxf(fmaxf((v).x + (B).x, (v).y + (B).y),               \
                         fmaxf((v).z + (B).z, (v).w + (B).w))

template<int RMODE>
__device__ __forceinline__ void run_seg(
    const float* __restrict__& pA, const float* __restrict__& pB, int n,
    bool c1p, bool c2p, const int fcl[3],
    const float4 B0, const float4 B1, Acc* aA, Acc* aB)
{
#pragma unroll 4
    for (int i = 0; i < n; ++i) {
        {
            float4 vA = *(const float4*)(pA + fcl[0]);
            float4 vB = *(const float4*)(pB + fcl[0]);
            upd<RMODE>(aA[0], TREE(vA, B0), TREE(vA, B1));
            upd<RMODE>(aB[0], TREE(vB, B0), TREE(vB, B1));
        }
        if (c1p) {
            float4 vA = *(const float4*)(pA + fcl[1]);
            float4 vB = *(const float4*)(pB + fcl[1]);
            upd<RMODE>(aA[1], TREE(vA, B0), TREE(vA, B1));
            upd<RMODE>(aB[1], TREE(vB, B0), TREE(vB, B1));
        }
        if (c2p) {
            float4 vA = *(const float4*)(pA + fcl[2]);
            float4 vB = *(const float4*)(pB + fcl[2]);
            upd<RMODE>(aA[2], TREE(vA, B0), TREE(vA, B1));
            upd<RMODE>(aB[2], TREE(vB, B0), TREE(vB, B1));
        }
        pA += PLANE; pB += PLANE;
    }
}

__global__ __launch_bounds__(256) void crop_pool_kernel(
    const float* __restrict__ fm, const int* __restrict__ corners,
    const int* __restrict__ scale_p, float* __restrict__ out)
{
    const int lane = threadIdx.x & 63;
    const int wid  = threadIdx.x >> 6;   // 0..3
    const int bp   = blockIdx.x >> 4;    // 16 consecutive blocks per proposal
    const int cg   = blockIdx.x & 15;
    const int slot = cg * 4 + wid;       // 0..63
    const int cA   = slot;
    const int cB   = slot + 64;
    const int b    = bp >> 6;            // P = 64

    const float inv = 1.0f / (float)scale_p[0];   // uniform; exact-floor mul

    // Per-axis bounds (k: 0->D, 1->H, 2->W), uniform -> SGPR.
    int s[3], e[3], m0a[3], m1a[3];
#pragma unroll
    for (int k = 0; k < 3; ++k) {
        int c0 = corners[(bp * 2 + 0) * 3 + k];
        int c1 = corners[(bp * 2 + 1) * 3 + k];
        int p1v = (int)((float)c0 * inv);     // == c0/scale (c0 in [0,95])
        p1v = p1v > 21 ? 21 : p1v;
        int p2v = (int)((float)c1 * inv);
        if (p2v - p1v < 2) p2v = p1v + 2;
        int ee = p2v < 24 ? p2v : 24;
        int n  = ee - p1v;                    // 2..23
        s[k]   = __builtin_amdgcn_readfirstlane(p1v);
        e[k]   = __builtin_amdgcn_readfirstlane(ee);
        m0a[k] = __builtin_amdgcn_readfirstlane(p1v + ((n + 1) >> 1)); // r0 end
        m1a[k] = __builtin_amdgcn_readfirstlane(p1v + (n >> 1));       // r1 start
    }

    const int sh  = s[1], eh = e[1], nh = eh - sh;
    const int m0h = m0a[1], m1h = m1a[1];
    const int sw  = s[2], ew = e[2], m0w = m0a[2], m1w = m1a[2];

    const int qb = sw & ~3;                            // aligned w base
    const int Q  = ((sw & 3) + (ew - sw) + 3) >> 2;    // quads per row, 1..7
    const int R  = 64 / Q;                             // rows per sweep, >= 9

    // lane/Q via exact magic multiply (Q<=7, lane<=63)
    const unsigned M = (65536u + (unsigned)Q - 1) / (unsigned)Q;
    const int r = (int)(((unsigned)lane * M) >> 16);
    const int q = lane - r * Q;
    const int wbase = qb + 4 * q;                      // 4-aligned, <= 20

    const bool c1p = nh > R;                 // wave-uniform chunk presence
    const bool c2p = nh > 2 * R;

    // Shared w-biases (row validity lives in the h-masks instead)
    float4 B0, B1;
    {
        int wt;
        wt = wbase + 0;
        B0.x = (wt >= sw  && wt < m0w) ? 0.0f : NI;
        B1.x = (wt >= m1w && wt < ew ) ? 0.0f : NI;
        wt = wbase + 1;
        B0.y = (wt >= sw  && wt < m0w) ? 0.0f : NI;
        B1.y = (wt >= m1w && wt < ew ) ? 0.0f : NI;
        wt = wbase + 2;
        B0.z = (wt >= sw  && wt < m0w) ? 0.0f : NI;
        B1.z = (wt >= m1w && wt < ew ) ? 0.0f : NI;
        wt = wbase + 3;
        B0.w = (wt >= sw  && wt < m0w) ? 0.0f : NI;
        B1.w = (wt >= m1w && wt < ew ) ? 0.0f : NI;
    }

    // Per-chunk row state: clamped offset + h-masks (validity folded in)
    int  fcl[3];
    bool h0m[3], h1m[3];
#pragma unroll
    for (int K = 0; K < 3; ++K) {
        const int  h  = sh + K * R + r;
        const bool va = h < eh;
        const int  f  = h * 24 + wbase;
        fcl[K] = f < (PLANE - 4) ? f : (PLANE - 4);
        h0m[K] = va && (h <  m0h);
        h1m[K] = va && (h >= m1h);
    }

    Acc aA[3], aB[3];
#pragma unroll
    for (int K = 0; K < 3; ++K) {
        aA[K].v00=NI; aA[K].v01=NI; aA[K].v10=NI; aA[K].v11=NI;
        aB[K].v00=NI; aB[K].v01=NI; aB[K].v10=NI; aB[K].v11=NI;
    }

    const float* __restrict__ pA =
        fm + ((size_t)(b * Cc + cA)) * VOL + (size_t)s[0] * PLANE;
    const float* __restrict__ pB =
        fm + ((size_t)(b * Cc + cB)) * VOL + (size_t)s[0] * PLANE;

    run_seg<0>(pA, pB, m1a[0] - s[0],   c1p, c2p, fcl, B0, B1, aA, aB);
    run_seg<2>(pA, pB, m0a[0] - m1a[0], c1p, c2p, fcl, B0, B1, aA, aB);
    run_seg<1>(pA, pB, e[0]  - m0a[0],  c1p, c2p, fcl, B0, B1, aA, aB);

    // Merge chunks with per-chunk h-masks into 8 octants j = dr*4+hr*2+wr.
    float oA[8], oB[8];
#pragma unroll
    for (int j = 0; j < 8; ++j) { oA[j] = NI; oB[j] = NI; }
#pragma unroll
    for (int K = 0; K < 3; ++K) {
        if (K == 1 && !c1p) continue;
        if (K == 2 && !c2p) continue;
        oA[0] = fmaxf(oA[0], h0m[K] ? aA[K].v00 : NI);
        oA[1] = fmaxf(oA[1], h0m[K] ? aA[K].v01 : NI);
        oA[2] = fmaxf(oA[2], h1m[K] ? aA[K].v00 : NI);
        oA[3] = fmaxf(oA[3], h1m[K] ? aA[K].v01 : NI);
        oA[4] = fmaxf(oA[4], h0m[K] ? aA[K].v10 : NI);
        oA[5] = fmaxf(oA[5], h0m[K] ? aA[K].v11 : NI);
        oA[6] = fmaxf(oA[6], h1m[K] ? aA[K].v10 : NI);
        oA[7] = fmaxf(oA[7], h1m[K] ? aA[K].v11 : NI);
        oB[0] = fmaxf(oB[0], h0m[K] ? aB[K].v00 : NI);
        oB[1] = fmaxf(oB[1], h0m[K] ? aB[K].v01 : NI);
        oB[2] = fmaxf(oB[2], h1m[K] ? aB[K].v00 : NI);
        oB[3] = fmaxf(oB[3], h1m[K] ? aB[K].v01 : NI);
        oB[4] = fmaxf(oB[4], h0m[K] ? aB[K].v10 : NI);
        oB[5] = fmaxf(oB[5], h0m[K] ? aB[K].v11 : NI);
        oB[6] = fmaxf(oB[6], h1m[K] ? aB[K].v10 : NI);
        oB[7] = fmaxf(oB[7], h1m[K] ? aB[K].v11 : NI);
    }

    // Channel fold: lanes<32 keep A, lanes>=32 keep B (one xor-32 exchange).
    const bool lo = lane < 32;
    float x[8];
#pragma unroll
    for (int j = 0; j < 8; ++j) {
        float keep = lo ? oA[j] : oB[j];
        float send = lo ? oB[j] : oA[j];
        x[j] = fmaxf(keep, __shfl_xor(send, 32));
    }
    // Select-exchange reduce over 32-lane halves (octant bit -> lane bit).
    const bool b0 = lane & 1, b1 = lane & 2, b2 = lane & 4;
    float m0_ = fmaxf(b0 ? x[1] : x[0], __shfl_xor(b0 ? x[0] : x[1], 1));
    float m1_ = fmaxf(b0 ? x[3] : x[2], __shfl_xor(b0 ? x[2] : x[3], 1));
    float m2_ = fmaxf(b0 ? x[5] : x[4], __shfl_xor(b0 ? x[4] : x[5], 1));
    float m3_ = fmaxf(b0 ? x[7] : x[6], __shfl_xor(b0 ? x[6] : x[7], 1));
    float n0_ = fmaxf(b1 ? m1_ : m0_, __shfl_xor(b1 ? m0_ : m1_, 2));
    float n1_ = fmaxf(b1 ? m3_ : m2_, __shfl_xor(b1 ? m2_ : m3_, 2));
    float v   = fmaxf(b2 ? n1_ : n0_, __shfl_xor(b2 ? n0_ : n1_, 4));
    v = fmaxf(v, __shfl_xor(v, 8));
    v = fmaxf(v, __shfl_xor(v, 16));

    if ((lane & 31) < 8) {
        const int cc = lo ? cA : cB;
        out[((size_t)bp * Cc + cc) * 8 + (lane & 7)] = v;
    }
}

extern "C" void kernel_launch(void* const* d_in, const int* in_sizes, int n_in,
                              void* d_out, int out_size, void* d_ws, size_t ws_size,
                              hipStream_t stream) {
    const float* fm      = (const float*)d_in[0];
    const int*   corners = (const int*)d_in[1];
    const int*   scale   = (const int*)d_in[2];
    float*       out     = (float*)d_out;

    dim3 grid(Bc * Pc * 16);   // 4096 blocks: one wave per (proposal, ch-pair)
    dim3 block(256);
    crop_pool_kernel<<<grid, block, 0, stream>>>(fm, corners, scale, out);
}

// Round 10
// 21.689 us; speedup vs baseline: 1.0900x; 1.0900x over previous
//
#include <hip/hip_runtime.h>
#include <math.h>

#define Bc 4
#define Cc 128
#define Pc 64
#define PLANE 576      // 24*24
#define VOL   13824    // 24^3
#define NI    (-INFINITY)

// One wave per (proposal, channel-pair {c, c+64}). NEW: when the h-crop fits
// in 3 chunks of 32/Q rows (~97% of proposals), the wave splits into two
// 32-lane halves covering planes d and d+1 per step (S=2) -> half the
// d-steps, half the wasted lanes. d-region membership is a per-lane flag
// pair (the xor-32 epilogue exchange merges the two halves AND folds
// channel B in one step). w-biases shared across chunks; row validity in
// h-masks; clamped loads discarded by masks (max idempotent).

#define TREE(v, B) fmaxf(fmaxf((v).x + (B).x, (v).y + (B).y),               \
                         fmaxf((v).z + (B).z, (v).w + (B).w))

__global__ __launch_bounds__(256) void crop_pool_kernel(
    const float* __restrict__ fm, const int* __restrict__ corners,
    const int* __restrict__ scale_p, float* __restrict__ out)
{
    const int lane = threadIdx.x & 63;
    const int wid  = threadIdx.x >> 6;   // 0..3
    const int bp   = blockIdx.x >> 4;    // 16 consecutive blocks per proposal
    const int cg   = blockIdx.x & 15;
    const int slot = cg * 4 + wid;       // 0..63
    const int cA   = slot;
    const int cB   = slot + 64;
    const int b    = bp >> 6;            // P = 64

    const float inv = 1.0f / (float)scale_p[0];   // uniform; exact-floor mul

    // Per-axis bounds (k: 0->D, 1->H, 2->W), uniform -> SGPR.
    int s[3], e[3], m0a[3], m1a[3];
#pragma unroll
    for (int k = 0; k < 3; ++k) {
        int c0 = corners[(bp * 2 + 0) * 3 + k];
        int c1 = corners[(bp * 2 + 1) * 3 + k];
        int p1v = (int)((float)c0 * inv);     // == c0/scale (c0 in [0,95])
        p1v = p1v > 21 ? 21 : p1v;
        int p2v = (int)((float)c1 * inv);
        if (p2v - p1v < 2) p2v = p1v + 2;
        int ee = p2v < 24 ? p2v : 24;
        int n  = ee - p1v;                    // 2..23
        s[k]   = __builtin_amdgcn_readfirstlane(p1v);
        e[k]   = __builtin_amdgcn_readfirstlane(ee);
        m0a[k] = __builtin_amdgcn_readfirstlane(p1v + ((n + 1) >> 1)); // r0 end
        m1a[k] = __builtin_amdgcn_readfirstlane(p1v + (n >> 1));       // r1 start
    }

    const int sd = s[0], ed = e[0], m0d = m0a[0], m1d = m1a[0];
    const int sh = s[1], eh = e[1], nh = eh - sh;
    const int m0h = m0a[1], m1h = m1a[1];
    const int sw = s[2], ew = e[2], m0w = m0a[2], m1w = m1a[2];

    const int qb = sw & ~3;                            // aligned w base
    const int Q  = ((sw & 3) + (ew - sw) + 3) >> 2;    // quads per row, 1..7

    // Magic for /Q (exact for dividend < 2^16/(Q-1); we divide <= 64)
    const unsigned M = (65536u + (unsigned)Q - 1) / (unsigned)Q;
    const int R2 = (int)((32u * M) >> 16);             // 32/Q
    const bool s2ok = nh <= 3 * R2;                    // 2-plane mode fits 3 chunks
    const int S     = s2ok ? 2 : 1;
    const int Reff  = s2ok ? R2 : (int)((64u * M) >> 16);
    const int lm    = s2ok ? (lane & 31) : lane;
    const int halfv = s2ok ? (lane >> 5) : 0;          // which d-plane this lane covers

    const int r = (int)(((unsigned)lm * M) >> 16);     // row within chunk
    const int q = lm - r * Q;
    const int wbase = qb + 4 * q;                      // 4-aligned, <= 20

    const bool c1p = nh > Reff;              // wave-uniform chunk presence
    const bool c2p = nh > 2 * Reff;

    // Shared w-biases (row validity lives in the h-masks instead)
    float4 B0, B1;
    {
        int wt;
        wt = wbase + 0;
        B0.x = (wt >= sw  && wt < m0w) ? 0.0f : NI;
        B1.x = (wt >= m1w && wt < ew ) ? 0.0f : NI;
        wt = wbase + 1;
        B0.y = (wt >= sw  && wt < m0w) ? 0.0f : NI;
        B1.y = (wt >= m1w && wt < ew ) ? 0.0f : NI;
        wt = wbase + 2;
        B0.z = (wt >= sw  && wt < m0w) ? 0.0f : NI;
        B1.z = (wt >= m1w && wt < ew ) ? 0.0f : NI;
        wt = wbase + 3;
        B0.w = (wt >= sw  && wt < m0w) ? 0.0f : NI;
        B1.w = (wt >= m1w && wt < ew ) ? 0.0f : NI;
    }

    // Per-chunk row state: clamped in-plane offset + h-masks (validity folded)
    int  fcl[3];
    bool h0m[3], h1m[3];
#pragma unroll
    for (int K = 0; K < 3; ++K) {
        const int  hrow = K * Reff + r;
        const int  h    = sh + hrow;
        const bool va   = hrow < nh;
        const int  f    = h * 24 + wbase;
        fcl[K] = f < (PLANE - 4) ? f : (PLANE - 4);
        h0m[K] = va && (h <  m0h);
        h1m[K] = va && (h >= m1h);
    }

    struct Acc { float v00, v01, v10, v11; } aA[3], aB[3];
#pragma unroll
    for (int K = 0; K < 3; ++K) {
        aA[K].v00=NI; aA[K].v01=NI; aA[K].v10=NI; aA[K].v11=NI;
        aB[K].v00=NI; aB[K].v01=NI; aB[K].v10=NI; aB[K].v11=NI;
    }

    const float* __restrict__ pA0 = fm + ((size_t)(b * Cc + cA)) * VOL;
    const float* __restrict__ pB0 = fm + ((size_t)(b * Cc + cB)) * VOL;
    const int emax = ed - 1;

    for (int d = sd; d < ed; d += S) {
        const int  dh  = d + halfv;               // per-lane plane index
        const int  dcl = dh < emax ? dh : emax;   // clamp (dup of last plane ok)
        const bool f0  = dcl <  m0d;              // d-region flags
        const bool f1  = dcl >= m1d;
        const int  ob  = dcl * PLANE;

#define CH(K) {                                                             \
        float4 vA = *(const float4*)(pA0 + ob + fcl[K]);                    \
        float4 vB = *(const float4*)(pB0 + ob + fcl[K]);                    \
        float t0A = TREE(vA, B0), t1A = TREE(vA, B1);                       \
        float t0B = TREE(vB, B0), t1B = TREE(vB, B1);                       \
        aA[K].v00 = fmaxf(aA[K].v00, f0 ? t0A : NI);                        \
        aA[K].v01 = fmaxf(aA[K].v01, f0 ? t1A : NI);                        \
        aA[K].v10 = fmaxf(aA[K].v10, f1 ? t0A : NI);                        \
        aA[K].v11 = fmaxf(aA[K].v11, f1 ? t1A : NI);                        \
        aB[K].v00 = fmaxf(aB[K].v00, f0 ? t0B : NI);                        \
        aB[K].v01 = fmaxf(aB[K].v01, f0 ? t1B : NI);                        \
        aB[K].v10 = fmaxf(aB[K].v10, f1 ? t0B : NI);                        \
        aB[K].v11 = fmaxf(aB[K].v11, f1 ? t1B : NI);                        \
    }
        CH(0)
        if (c1p) CH(1)
        if (c2p) CH(2)
#undef CH
    }

    // Merge chunks with per-chunk h-masks into 8 octants j = dr*4+hr*2+wr.
    float oA[8], oB[8];
#pragma unroll
    for (int j = 0; j < 8; ++j) { oA[j] = NI; oB[j] = NI; }
#pragma unroll
    for (int K = 0; K < 3; ++K) {
        if (K == 1 && !c1p) continue;
        if (K == 2 && !c2p) continue;
        oA[0] = fmaxf(oA[0], h0m[K] ? aA[K].v00 : NI);
        oA[1] = fmaxf(oA[1], h0m[K] ? aA[K].v01 : NI);
        oA[2] = fmaxf(oA[2], h1m[K] ? aA[K].v00 : NI);
        oA[3] = fmaxf(oA[3], h1m[K] ? aA[K].v01 : NI);
        oA[4] = fmaxf(oA[4], h0m[K] ? aA[K].v10 : NI);
        oA[5] = fmaxf(oA[5], h0m[K] ? aA[K].v11 : NI);
        oA[6] = fmaxf(oA[6], h1m[K] ? aA[K].v10 : NI);
        oA[7] = fmaxf(oA[7], h1m[K] ? aA[K].v11 : NI);
        oB[0] = fmaxf(oB[0], h0m[K] ? aB[K].v00 : NI);
        oB[1] = fmaxf(oB[1], h0m[K] ? aB[K].v01 : NI);
        oB[2] = fmaxf(oB[2], h1m[K] ? aB[K].v00 : NI);
        oB[3] = fmaxf(oB[3], h1m[K] ? aB[K].v01 : NI);
        oB[4] = fmaxf(oB[4], h0m[K] ? aB[K].v10 : NI);
        oB[5] = fmaxf(oB[5], h0m[K] ? aB[K].v11 : NI);
        oB[6] = fmaxf(oB[6], h1m[K] ? aB[K].v10 : NI);
        oB[7] = fmaxf(oB[7], h1m[K] ? aB[K].v11 : NI);
    }

    // xor-32 exchange: merges the two d-halves AND folds channel B.
    // lanes<32 end with A (both halves), lanes>=32 with B (both halves).
    const bool lo = lane < 32;
    float x[8];
#pragma unroll
    for (int j = 0; j < 8; ++j) {
        float keep = lo ? oA[j] : oB[j];
        float send = lo ? oB[j] : oA[j];
        x[j] = fmaxf(keep, __shfl_xor(send, 32));
    }
    // Select-exchange reduce over 32-lane halves (octant bit -> lane bit).
    const bool b0 = lane & 1, b1 = lane & 2, b2 = lane & 4;
    float m0_ = fmaxf(b0 ? x[1] : x[0], __shfl_xor(b0 ? x[0] : x[1], 1));
    float m1_ = fmaxf(b0 ? x[3] : x[2], __shfl_xor(b0 ? x[2] : x[3], 1));
    float m2_ = fmaxf(b0 ? x[5] : x[4], __shfl_xor(b0 ? x[4] : x[5], 1));
    float m3_ = fmaxf(b0 ? x[7] : x[6], __shfl_xor(b0 ? x[6] : x[7], 1));
    float n0_ = fmaxf(b1 ? m1_ : m0_, __shfl_xor(b1 ? m0_ : m1_, 2));
    float n1_ = fmaxf(b1 ? m3_ : m2_, __shfl_xor(b1 ? m2_ : m3_, 2));
    float v   = fmaxf(b2 ? n1_ : n0_, __shfl_xor(b2 ? n0_ : n1_, 4));
    v = fmaxf(v, __shfl_xor(v, 8));
    v = fmaxf(v, __shfl_xor(v, 16));

    if ((lane & 31) < 8) {
        const int cc = lo ? cA : cB;
        out[((size_t)bp * Cc + cc) * 8 + (lane & 7)] = v;
    }
}

extern "C" void kernel_launch(void* const* d_in, const int* in_sizes, int n_in,
                              void* d_out, int out_size, void* d_ws, size_t ws_size,
                              hipStream_t stream) {
    const float* fm      = (const float*)d_in[0];
    const int*   corners = (const int*)d_in[1];
    const int*   scale   = (const int*)d_in[2];
    float*       out     = (float*)d_out;

    dim3 grid(Bc * Pc * 16);   // 4096 blocks: one wave per (proposal, ch-pair)
    dim3 block(256);
    crop_pool_kernel<<<grid, block, 0, stream>>>(fm, corners, scale, out);
}